// Round 3
// baseline (20054.803 us; speedup 1.0000x reference)
//
#include <hip/hip_runtime.h>
#include <hip/hip_bf16.h>

// Seq2Seq GRU: persistent kernel, runtime dtype detection (fp32 vs bf16 inputs),
// internal bf16 staging for MFMA, fp32 master hidden state.
// enc: 2-layer GRU pipelined -> 257 phases; dec: 64 x (l0|l1|fc) -> 192 phases.

constexpr int HIDN = 1024;
constexpr int IND  = 256;
constexpr int BB   = 64;
constexpr int ET   = 256;
constexpr int DT   = 64;
constexpr int NBLK = 128;   // 0..63 layer0, 64..127 layer1
constexpr int NTHR = 256;   // 4 waves, batch-split

typedef __attribute__((ext_vector_type(8))) short short8;   // 8 x bf16
typedef __attribute__((ext_vector_type(4))) float f32x4;
typedef __attribute__((ext_vector_type(4))) float f4;
typedef __attribute__((ext_vector_type(4))) unsigned int u32x4;
typedef unsigned short u16;

// ---- bf16 staging buffer offsets (elements) ----
constexpr size_t O_SRC  = 0;                                  // [B][ET][IND]
constexpr size_t O_EWI0 = O_SRC  + (size_t)BB*ET*IND;
constexpr size_t O_EWH0 = O_EWI0 + (size_t)3*HIDN*IND;
constexpr size_t O_EWI1 = O_EWH0 + (size_t)3*HIDN*HIDN;
constexpr size_t O_EWH1 = O_EWI1 + (size_t)3*HIDN*HIDN;
constexpr size_t O_DWI0 = O_EWH1 + (size_t)3*HIDN*HIDN;
constexpr size_t O_DWH0 = O_DWI0 + (size_t)3*HIDN*IND;
constexpr size_t O_DWI1 = O_DWH0 + (size_t)3*HIDN*HIDN;
constexpr size_t O_DWH1 = O_DWI1 + (size_t)3*HIDN*HIDN;
constexpr size_t O_FCW  = O_DWH1 + (size_t)3*HIDN*HIDN;
constexpr size_t NBF    = O_FCW + (size_t)IND*HIDN;           // ~24.9M elems

// ---- fp32 bias buffer offsets ----
constexpr size_t F_EBI0=0, F_EBH0=3072, F_EBI1=6144, F_EBH1=9216,
                 F_DBI0=12288, F_DBH0=15360, F_DBI1=18432, F_DBH1=21504,
                 F_FCB=24576;
constexpr size_t NFB = 24832;

// ---- mutable state (4-byte words) ----
constexpr size_t H0M_W = 0;                            // fp32 [B][H]
constexpr size_t H1M_W = H0M_W + (size_t)BB*HIDN;
constexpr size_t Y0R_W = H1M_W + (size_t)BB*HIDN;      // bf16 ring x2 [B][H]
constexpr size_t H1B_W = Y0R_W + (size_t)BB*HIDN;
constexpr size_t DH0_W = H1B_W + (size_t)BB*HIDN;
constexpr size_t DH1_W = DH0_W + (size_t)BB*HIDN;
constexpr size_t PRD_W = DH1_W + (size_t)BB*HIDN;      // bf16 ring x2 [B][IND]
constexpr size_t TOT_W = PRD_W + (size_t)BB*IND/2*2;

__device__ unsigned g_bar[2];                          // {count, generation}
__device__ __align__(16) unsigned g_state[TOT_W];
__device__ __align__(16) u16   g_bf[NBF];
__device__ __align__(16) float g_fb[NFB];

__device__ __forceinline__ float bf2f(u16 x) {
  union { float f; unsigned u; } v; v.u = ((unsigned)x) << 16; return v.f;
}
__device__ __forceinline__ u16 f2bf(float f) {
  union { float f; unsigned u; } v; v.f = f;
  unsigned r = v.u + 0x7FFFu + ((v.u >> 16) & 1u);  // RNE
  return (u16)(r >> 16);
}
__device__ __forceinline__ float sigm(float x) { return 1.f / (1.f + __expf(-x)); }
__device__ __forceinline__ float tanh_(float x) {
  float e = __expf(2.f * x);
  return 1.f - 2.f / (e + 1.f);
}
__device__ __forceinline__ f32x4 mfma16(short8 a, short8 b, f32x4 c) {
  return __builtin_amdgcn_mfma_f32_16x16x32_bf16(a, b, c, 0, 0, 0);
}
__device__ __forceinline__ short8 ld8(const u16* p) { return *(const short8*)p; }

__device__ __forceinline__ void st_out(void* base, size_t idx, float v, int f32o) {
  if (f32o) ((float*)base)[idx] = v;
  else      ((u16*)base)[idx]   = f2bf(v);
}

// sense-reversing grid barrier (proved safe via release/acquire on gen)
__device__ __forceinline__ void grid_barrier() {
  __syncthreads();
  if (threadIdx.x == 0) {
    __threadfence();
    unsigned gen = __hip_atomic_load(&g_bar[1], __ATOMIC_RELAXED, __HIP_MEMORY_SCOPE_AGENT);
    unsigned n = __hip_atomic_fetch_add(&g_bar[0], 1u, __ATOMIC_ACQ_REL, __HIP_MEMORY_SCOPE_AGENT);
    if (n == (unsigned)(NBLK - 1)) {
      __hip_atomic_store(&g_bar[0], 0u, __ATOMIC_RELAXED, __HIP_MEMORY_SCOPE_AGENT);
      __hip_atomic_fetch_add(&g_bar[1], 1u, __ATOMIC_RELEASE, __HIP_MEMORY_SCOPE_AGENT);
    } else {
      while (__hip_atomic_load(&g_bar[1], __ATOMIC_RELAXED, __HIP_MEMORY_SCOPE_AGENT) == gen)
        __builtin_amdgcn_s_sleep(1);
    }
    __threadfence();
  }
  __syncthreads();
}

struct P { const void* in[20]; void* out; };

// dtype-aware conversion into bf16 staging (8 elems/iter)
__device__ __forceinline__ void conv_bf(size_t gtid, size_t gs,
    const void* src, u16* dst, size_t n, int isbf) {
  if (isbf) {
    const u32x4* s = (const u32x4*)src;  u32x4* d = (u32x4*)dst;
    for (size_t i = gtid; i < n / 8; i += gs) d[i] = s[i];
  } else {
    const f4* s = (const f4*)src;
    short8* d = (short8*)dst;
    for (size_t i = gtid; i < n / 8; i += gs) {
      f4 a = s[2 * i], b = s[2 * i + 1];
      short8 o;
      o[0]=(short)f2bf(a[0]); o[1]=(short)f2bf(a[1]);
      o[2]=(short)f2bf(a[2]); o[3]=(short)f2bf(a[3]);
      o[4]=(short)f2bf(b[0]); o[5]=(short)f2bf(b[1]);
      o[6]=(short)f2bf(b[2]); o[7]=(short)f2bf(b[3]);
      d[i] = o;
    }
  }
}
__device__ __forceinline__ void conv_f(size_t gtid, size_t gs,
    const void* src, float* dst, size_t n, int isbf) {
  if (isbf) { const u16* s = (const u16*)src;
    for (size_t i = gtid; i < n; i += gs) dst[i] = bf2f(s[i]);
  } else { const float* s = (const float*)src;
    for (size_t i = gtid; i < n; i += gs) dst[i] = s[i]; }
}

// GRU cell step, 16(batch) x 16(unit) tile per wave.
__device__ void gru_phase(int m0, int u0,
    const u16* __restrict__ X, int xstride, int Kx, const u16* __restrict__ Wi,
    const u16* __restrict__ Hb, const u16* __restrict__ Wh,
    const float* __restrict__ bi, const float* __restrict__ bh,
    float* __restrict__ hm, u16* __restrict__ hout,
    void* outb, size_t eo_base, int eo_bstride, int f32o)
{
  const int lane = threadIdx.x & 63;
  const int lo = lane & 15, quad = lane >> 4;
  f32x4 aR = {0.f,0.f,0.f,0.f}, aZ = aR, aIN = aR, aHN = aR;

  {  // x segment
    const u16* ax = X + (size_t)(m0 + lo) * xstride + quad * 8;
    const u16* w0 = Wi + (size_t)(u0 + lo) * Kx + quad * 8;
    const u16* w1 = w0 + (size_t)HIDN * Kx;
    const u16* w2 = w1 + (size_t)HIDN * Kx;
    for (int k = 0; k < Kx; k += 32) {
      short8 a = ld8(ax + k);
      aR  = mfma16(a, ld8(w0 + k), aR);
      aZ  = mfma16(a, ld8(w1 + k), aZ);
      aIN = mfma16(a, ld8(w2 + k), aIN);
    }
  }
  {  // h segment
    const u16* ah = Hb + (size_t)(m0 + lo) * HIDN + quad * 8;
    const u16* w0 = Wh + (size_t)(u0 + lo) * HIDN + quad * 8;
    const u16* w1 = w0 + (size_t)HIDN * HIDN;
    const u16* w2 = w1 + (size_t)HIDN * HIDN;
    for (int k = 0; k < HIDN; k += 32) {
      short8 a = ld8(ah + k);
      aR  = mfma16(a, ld8(w0 + k), aR);
      aZ  = mfma16(a, ld8(w1 + k), aZ);
      aHN = mfma16(a, ld8(w2 + k), aHN);
    }
  }
  const int u = u0 + lo;
  const float brz = bi[u] + bh[u];
  const float bzz = bi[HIDN + u] + bh[HIDN + u];
  const float bin = bi[2 * HIDN + u];
  const float bhn = bh[2 * HIDN + u];
#pragma unroll
  for (int i = 0; i < 4; ++i) {
    const int b = m0 + quad * 4 + i;
    float r = sigm(aR[i] + brz);
    float z = sigm(aZ[i] + bzz);
    float n = tanh_(aIN[i] + bin + r * (aHN[i] + bhn));
    float h = (1.f - z) * n + z * hm[(size_t)b * HIDN + u];
    hm[(size_t)b * HIDN + u] = h;
    hout[(size_t)b * HIDN + u] = f2bf(h);
    if (eo_bstride) st_out(outb, eo_base + (size_t)b * eo_bstride + u, h, f32o);
  }
}

// FC head: 16(batch) x 16(out) tile per wave, K = HIDN.
__device__ void fc_phase(int m0, int o0,
    const u16* __restrict__ Hb, const u16* __restrict__ W, const float* __restrict__ bias,
    void* outb, size_t base, int out_bstride, u16* __restrict__ predb, int f32o)
{
  const int lane = threadIdx.x & 63;
  const int lo = lane & 15, quad = lane >> 4;
  f32x4 acc = {0.f,0.f,0.f,0.f};
  const u16* ah = Hb + (size_t)(m0 + lo) * HIDN + quad * 8;
  const u16* w  = W + (size_t)(o0 + lo) * HIDN + quad * 8;
  for (int k = 0; k < HIDN; k += 32)
    acc = mfma16(ld8(ah + k), ld8(w + k), acc);
  const int o = o0 + lo;
  const float bv = bias[o];
#pragma unroll
  for (int i = 0; i < 4; ++i) {
    const int b = m0 + quad * 4 + i;
    float v = acc[i] + bv;
    st_out(outb, base + (size_t)b * out_bstride + o, v, f32o);
    predb[(size_t)b * IND + o] = f2bf(v);
  }
}

__global__ void __launch_bounds__(NTHR)
s2s_gru_main(P pr) {
  const int blk = blockIdx.x;
  const int wave = threadIdx.x >> 6;
  const int layer = blk >> 6;
  const int u0 = (blk & 63) * 16;
  const int m0 = wave * 16;

  // ---- dtype detection: probe 64 low-u16 exponent fields per input ----
  __shared__ int sflag[20];
  {
    const int wv = threadIdx.x >> 6, ln = threadIdx.x & 63;
    for (int i = wv; i < 20; i += 4) {
      const unsigned* p = (const unsigned*)pr.in[i];
      unsigned w = p[ln];
      unsigned e = (w >> 7) & 0xFFu;                 // exponent of low u16 as bf16
      unsigned long long m = __ballot(e >= 0x60u && e < 0xA0u);
      if (ln == 0) sflag[i] = (__popcll(m) >= 48) ? 1 : 0;   // 1 = bf16
    }
  }
  __syncthreads();
  const int f32o = sflag[0] ? 0 : 1;   // output dtype follows src

  // ---- staging conversion + state zeroing ----
  {
    const size_t gtid = (size_t)blk * NTHR + threadIdx.x;
    const size_t gs = (size_t)NBLK * NTHR;
    conv_bf(gtid, gs, pr.in[0],  g_bf + O_SRC,  (size_t)BB*ET*IND, sflag[0]);
    conv_bf(gtid, gs, pr.in[2],  g_bf + O_EWI0, (size_t)3*HIDN*IND,  sflag[2]);
    conv_bf(gtid, gs, pr.in[3],  g_bf + O_EWH0, (size_t)3*HIDN*HIDN, sflag[3]);
    conv_bf(gtid, gs, pr.in[6],  g_bf + O_EWI1, (size_t)3*HIDN*HIDN, sflag[6]);
    conv_bf(gtid, gs, pr.in[7],  g_bf + O_EWH1, (size_t)3*HIDN*HIDN, sflag[7]);
    conv_bf(gtid, gs, pr.in[10], g_bf + O_DWI0, (size_t)3*HIDN*IND,  sflag[10]);
    conv_bf(gtid, gs, pr.in[11], g_bf + O_DWH0, (size_t)3*HIDN*HIDN, sflag[11]);
    conv_bf(gtid, gs, pr.in[14], g_bf + O_DWI1, (size_t)3*HIDN*HIDN, sflag[14]);
    conv_bf(gtid, gs, pr.in[15], g_bf + O_DWH1, (size_t)3*HIDN*HIDN, sflag[15]);
    conv_bf(gtid, gs, pr.in[18], g_bf + O_FCW,  (size_t)IND*HIDN,    sflag[18]);
    conv_f(gtid, gs, pr.in[4],  g_fb + F_EBI0, 3*HIDN, sflag[4]);
    conv_f(gtid, gs, pr.in[5],  g_fb + F_EBH0, 3*HIDN, sflag[5]);
    conv_f(gtid, gs, pr.in[8],  g_fb + F_EBI1, 3*HIDN, sflag[8]);
    conv_f(gtid, gs, pr.in[9],  g_fb + F_EBH1, 3*HIDN, sflag[9]);
    conv_f(gtid, gs, pr.in[12], g_fb + F_DBI0, 3*HIDN, sflag[12]);
    conv_f(gtid, gs, pr.in[13], g_fb + F_DBH0, 3*HIDN, sflag[13]);
    conv_f(gtid, gs, pr.in[16], g_fb + F_DBI1, 3*HIDN, sflag[16]);
    conv_f(gtid, gs, pr.in[17], g_fb + F_DBH1, 3*HIDN, sflag[17]);
    conv_f(gtid, gs, pr.in[19], g_fb + F_FCB,  IND,    sflag[19]);
    for (size_t i = gtid; i < TOT_W; i += gs) g_state[i] = 0u;
  }
  grid_barrier();

  float* h0m = (float*)(g_state + H0M_W);
  float* h1m = (float*)(g_state + H1M_W);
  u16* y0r = (u16*)(g_state + Y0R_W);
  u16* h1b = (u16*)(g_state + H1B_W);
  u16* dh0 = (u16*)(g_state + DH0_W);
  u16* dh1 = (u16*)(g_state + DH1_W);
  u16* prd = (u16*)(g_state + PRD_W);
  const u16* srcb = g_bf + O_SRC;

  // output element offsets: [pred | enc_state | dec_state]
  const size_t EO_ENC = (size_t)BB * DT * IND;
  const size_t EO_DEC = EO_ENC + (size_t)BB * ET * HIDN;
  const size_t SH = (size_t)BB * HIDN;
  const size_t SP = (size_t)BB * IND;

  // ---------------- encoder: pipelined, 257 phases ----------------
  for (int ph = 0; ph <= ET; ++ph) {
    if (layer == 0) {
      if (ph < ET) {
        gru_phase(m0, u0,
                  srcb + (size_t)ph * IND, ET * IND, IND, g_bf + O_EWI0,
                  y0r + (size_t)(ph & 1) * SH, g_bf + O_EWH0,
                  g_fb + F_EBI0, g_fb + F_EBH0, h0m,
                  y0r + (size_t)((ph + 1) & 1) * SH,
                  pr.out, 0, 0, f32o);
      }
    } else {
      if (ph >= 1) {
        const int t = ph - 1;
        gru_phase(m0, u0,
                  y0r + (size_t)(ph & 1) * SH, HIDN, HIDN, g_bf + O_EWI1,
                  h1b + (size_t)(t & 1) * SH, g_bf + O_EWH1,
                  g_fb + F_EBI1, g_fb + F_EBH1, h1m,
                  h1b + (size_t)((t + 1) & 1) * SH,
                  pr.out, EO_ENC + (size_t)t * HIDN, ET * HIDN, f32o);
      }
    }
    grid_barrier();
  }

  // ---------------- decoder: 64 steps x 3 phases ----------------
  for (int s = 0; s < DT; ++s) {
    if (layer == 0) {
      const u16* x   = (s == 0) ? (prd + SP) : (prd + (size_t)((s - 1) & 1) * SP);
      const u16* hin = (s == 0) ? (y0r)      : (dh0 + (size_t)((s - 1) & 1) * SH);
      gru_phase(m0, u0, x, IND, IND, g_bf + O_DWI0, hin, g_bf + O_DWH0,
                g_fb + F_DBI0, g_fb + F_DBH0, h0m,
                dh0 + (size_t)(s & 1) * SH, pr.out, 0, 0, f32o);
    }
    grid_barrier();
    if (layer == 1) {
      const u16* hin = (s == 0) ? (h1b) : (dh1 + (size_t)((s - 1) & 1) * SH);
      gru_phase(m0, u0, dh0 + (size_t)(s & 1) * SH, HIDN, HIDN, g_bf + O_DWI1,
                hin, g_bf + O_DWH1,
                g_fb + F_DBI1, g_fb + F_DBH1, h1m,
                dh1 + (size_t)(s & 1) * SH,
                pr.out, EO_DEC + (size_t)s * HIDN, DT * HIDN, f32o);
    }
    grid_barrier();
    if (layer == 0 && (blk & 63) < 16) {
      fc_phase(m0, (blk & 63) * 16, dh1 + (size_t)(s & 1) * SH,
               g_bf + O_FCW, g_fb + F_FCB,
               pr.out, (size_t)s * IND, DT * IND,
               prd + (size_t)(s & 1) * SP, f32o);
    }
    grid_barrier();
  }
}

extern "C" void kernel_launch(void* const* d_in, const int* in_sizes, int n_in,
                              void* d_out, int out_size, void* d_ws, size_t ws_size,
                              hipStream_t stream) {
  P p;
  for (int i = 0; i < 20; ++i) p.in[i] = d_in[i];
  p.out = d_out;
  s2s_gru_main<<<dim3(NBLK), dim3(NTHR), 0, stream>>>(p);
}

// Round 5
// 11022.614 us; speedup vs baseline: 1.8194x; 1.8194x over previous
//
#include <hip/hip_runtime.h>
#include <hip/hip_bf16.h>

// Seq2Seq GRU: persistent kernel. Weights pre-swizzled into MFMA-fragment
// streams; waves split K with LDS reduction; 256 blocks; 2-level grid barrier.
// Round 5: gru_B templated (compile-time NBT/KTX/XSW) to avoid clang ICE.

constexpr int HIDN = 1024;
constexpr int IND  = 256;
constexpr int BB   = 64;
constexpr int ET   = 256;
constexpr int DT   = 64;
constexpr int NBLK = 256;
constexpr int NTHR = 256;   // 4 waves

typedef __attribute__((ext_vector_type(8))) short short8;   // 8 x bf16
typedef __attribute__((ext_vector_type(4))) float f32x4;
typedef __attribute__((ext_vector_type(4))) float f4;
typedef unsigned short u16;

// ---- bf16 staging (swizzled) offsets (elements) ----
constexpr size_t O_SRC  = 0;                                  // [t][bt4][ks][512]
constexpr size_t O_EWI0 = O_SRC  + (size_t)BB*ET*IND;
constexpr size_t O_EWH0 = O_EWI0 + (size_t)3*HIDN*IND;
constexpr size_t O_EWI1 = O_EWH0 + (size_t)3*HIDN*HIDN;
constexpr size_t O_EWH1 = O_EWI1 + (size_t)3*HIDN*HIDN;
constexpr size_t O_DWI0 = O_EWH1 + (size_t)3*HIDN*HIDN;
constexpr size_t O_DWH0 = O_DWI0 + (size_t)3*HIDN*IND;
constexpr size_t O_DWI1 = O_DWH0 + (size_t)3*HIDN*HIDN;
constexpr size_t O_DWH1 = O_DWI1 + (size_t)3*HIDN*HIDN;
constexpr size_t O_FCW  = O_DWH1 + (size_t)3*HIDN*HIDN;
constexpr size_t NBF    = O_FCW + (size_t)IND*HIDN;

// ---- fp32 bias offsets ----
constexpr size_t F_EBI0=0, F_EBH0=3072, F_EBI1=6144, F_EBH1=9216,
                 F_DBI0=12288, F_DBH0=15360, F_DBI1=18432, F_DBH1=21504,
                 F_FCB=24576;
constexpr size_t NFB = 24832;

// ---- mutable state (4-byte words) ----
constexpr size_t H0M_W = 0;                            // fp32 [B][H]
constexpr size_t H1M_W = H0M_W + (size_t)BB*HIDN;
constexpr size_t Y0R_W = H1M_W + (size_t)BB*HIDN;      // bf16 ring x2 [B][H]
constexpr size_t H1B_W = Y0R_W + (size_t)BB*HIDN;
constexpr size_t DH0_W = H1B_W + (size_t)BB*HIDN;
constexpr size_t DH1_W = DH0_W + (size_t)BB*HIDN;
constexpr size_t PRD_W = DH1_W + (size_t)BB*HIDN;      // bf16 ring x2 [B][IND]
constexpr size_t TOT_W = PRD_W + (size_t)BB*IND/2*2;

__device__ unsigned g_bar2[320];                       // leaves[8*32], root@256, gen@288
__device__ __align__(16) unsigned g_state[TOT_W];
__device__ __align__(16) u16   g_bf[NBF];
__device__ __align__(16) float g_fb[NFB];

__device__ __forceinline__ float bf2f(u16 x) {
  union { float f; unsigned u; } v; v.u = ((unsigned)x) << 16; return v.f;
}
__device__ __forceinline__ u16 f2bf(float f) {
  union { float f; unsigned u; } v; v.f = f;
  unsigned r = v.u + 0x7FFFu + ((v.u >> 16) & 1u);
  return (u16)(r >> 16);
}
__device__ __forceinline__ float sigm(float x) { return 1.f / (1.f + __expf(-x)); }
__device__ __forceinline__ float tanh_(float x) {
  float e = __expf(2.f * x);
  return 1.f - 2.f / (e + 1.f);
}
__device__ __forceinline__ f32x4 mfma16(short8 a, short8 b, f32x4 c) {
  return __builtin_amdgcn_mfma_f32_16x16x32_bf16(a, b, c, 0, 0, 0);
}
__device__ __forceinline__ short8 ld8(const u16* p) { return *(const short8*)p; }
__device__ __forceinline__ void st_out(void* base, size_t idx, float v, int f32o) {
  if (f32o) ((float*)base)[idx] = v;
  else      ((u16*)base)[idx]   = f2bf(v);
}

// two-level grid barrier: 8 groups x 32 blocks; spin on generation counter
__device__ __forceinline__ void grid_barrier() {
  __syncthreads();
  if (threadIdx.x == 0) {
    __threadfence();
    unsigned* leaf = &g_bar2[(blockIdx.x & 7) * 32];
    unsigned* root = &g_bar2[256];
    unsigned* genp = &g_bar2[288];
    unsigned gen = __hip_atomic_load(genp, __ATOMIC_RELAXED, __HIP_MEMORY_SCOPE_AGENT);
    unsigned n = __hip_atomic_fetch_add(leaf, 1u, __ATOMIC_ACQ_REL, __HIP_MEMORY_SCOPE_AGENT);
    bool released = false;
    if (n == 31u) {
      __hip_atomic_store(leaf, 0u, __ATOMIC_RELAXED, __HIP_MEMORY_SCOPE_AGENT);
      unsigned r = __hip_atomic_fetch_add(root, 1u, __ATOMIC_ACQ_REL, __HIP_MEMORY_SCOPE_AGENT);
      if (r == 7u) {
        __hip_atomic_store(root, 0u, __ATOMIC_RELAXED, __HIP_MEMORY_SCOPE_AGENT);
        __hip_atomic_fetch_add(genp, 1u, __ATOMIC_RELEASE, __HIP_MEMORY_SCOPE_AGENT);
        released = true;
      }
    }
    if (!released) {
      while (__hip_atomic_load(genp, __ATOMIC_RELAXED, __HIP_MEMORY_SCOPE_AGENT) == gen)
        __builtin_amdgcn_s_sleep(1);
    }
    __threadfence();
  }
  __syncthreads();
}

struct P { const void* in[20]; void* out; };

// ---- prologue converters ----
// weight -> fragment stream: dst block(ut,ks,g) = ((ut*Kt+ks)*gates+g)*512,
// entry lane*8+j = W[g*rowsPerGate + ut*16 + (lane&15)][ks*32 + (lane>>4)*8 + j]
__device__ void conv_w(size_t gtid, size_t gs, const void* src, u16* dst,
                       int K, int gates, int rowsPerGate, int isbf) {
  const int Kt = K >> 5;
  const size_t n8 = (size_t)gates * rowsPerGate * K / 8;
  for (size_t i = gtid; i < n8; i += gs) {
    int lane = (int)(i & 63);
    size_t blk = i >> 6;
    int g = (int)(blk % gates);
    size_t rest = blk / gates;
    int ks = (int)(rest % Kt);
    int ut = (int)(rest / Kt);
    int row = g * rowsPerGate + ut * 16 + (lane & 15);
    int col = ks * 32 + (lane >> 4) * 8;
    size_t e = (size_t)row * K + col;
    short8 o;
    if (isbf) {
      o = *(const short8*)((const u16*)src + e);
    } else {
      const f4 a = *(const f4*)((const float*)src + e);
      const f4 b = *(const f4*)((const float*)src + e + 4);
      o[0]=(short)f2bf(a[0]); o[1]=(short)f2bf(a[1]);
      o[2]=(short)f2bf(a[2]); o[3]=(short)f2bf(a[3]);
      o[4]=(short)f2bf(b[0]); o[5]=(short)f2bf(b[1]);
      o[6]=(short)f2bf(b[2]); o[7]=(short)f2bf(b[3]);
    }
    ((short8*)dst)[i] = o;
  }
}
// src [b][t][i] -> [t][bt4][ks][512]
__device__ void conv_src(size_t gtid, size_t gs, const void* src, u16* dst, int isbf) {
  const size_t n8 = (size_t)BB * ET * IND / 8;
  for (size_t i = gtid; i < n8; i += gs) {
    int lane = (int)(i & 63);
    size_t blk = i >> 6;
    int ks = (int)(blk & 7);
    int bt4 = (int)((blk >> 3) & 3);
    int t = (int)(blk >> 5);
    int b = bt4 * 16 + (lane & 15);
    int col = ks * 32 + (lane >> 4) * 8;
    size_t e = ((size_t)b * ET + t) * IND + col;
    short8 o;
    if (isbf) {
      o = *(const short8*)((const u16*)src + e);
    } else {
      const f4 a = *(const f4*)((const float*)src + e);
      const f4 b2 = *(const f4*)((const float*)src + e + 4);
      o[0]=(short)f2bf(a[0]); o[1]=(short)f2bf(a[1]);
      o[2]=(short)f2bf(a[2]); o[3]=(short)f2bf(a[3]);
      o[4]=(short)f2bf(b2[0]); o[5]=(short)f2bf(b2[1]);
      o[6]=(short)f2bf(b2[2]); o[7]=(short)f2bf(b2[3]);
    }
    ((short8*)dst)[i] = o;
  }
}
__device__ void conv_f(size_t gtid, size_t gs, const void* src, float* dst,
                       size_t n, int isbf) {
  if (isbf) { const u16* s = (const u16*)src;
    for (size_t i = gtid; i < n; i += gs) dst[i] = bf2f(s[i]);
  } else { const float* s = (const float*)src;
    for (size_t i = gtid; i < n; i += gs) dst[i] = s[i]; }
}

// ---- GRU phase (templated: all trip counts compile-time constant) ----
// Block = (ut, mb0, NBT batch tiles). 4 waves split K; LDS reduce + gate math.
// KTX = Kx/32 (x-segment K-tiles). XSW: x comes from swizzled stream.
template<int NBT, int KTX, bool XSW>
__device__ void gru_B(int ut, int mb0,
    const u16* __restrict__ xp, const u16* __restrict__ swWi,
    const u16* __restrict__ swWh, const u16* __restrict__ hplain,
    const float* __restrict__ bi, const float* __restrict__ bh,
    float* __restrict__ hm, u16* __restrict__ hout,
    void* outb, size_t eo_base, size_t eo_bstride, int f32o,
    float* lds)
{
  const int tid = threadIdx.x;
  const int lane = tid & 63, w = tid >> 6;
  const int lo = lane & 15, quad = lane >> 4;
  const f32x4 z4 = {0.f,0.f,0.f,0.f};
  f32x4 aR[NBT], aZ[NBT], aIN[NBT], aHN[NBT];
#pragma unroll
  for (int m = 0; m < NBT; ++m) { aR[m]=z4; aZ[m]=z4; aIN[m]=z4; aHN[m]=z4; }

  constexpr int XC = KTX / 4;        // x-steps per wave
  {  // x segment
    const int s0 = w * XC;
#pragma unroll
    for (int kk = 0; kk < XC; ++kk) {
      const int ks = s0 + kk;
      const u16* wb = swWi + (size_t)((ut * KTX + ks) * 3) * 512 + lane * 8;
      short8 w0 = ld8(wb), w1 = ld8(wb + 512), w2 = ld8(wb + 1024);
#pragma unroll
      for (int m = 0; m < NBT; ++m) {
        short8 a;
        if (XSW) a = ld8(xp + (size_t)(((mb0 >> 4) + m) * KTX + ks) * 512 + lane * 8);
        else     a = ld8(xp + (size_t)(mb0 + m * 16 + lo) * (KTX * 32) + ks * 32 + quad * 8);
        aR[m]  = mfma16(a, w0, aR[m]);
        aZ[m]  = mfma16(a, w1, aZ[m]);
        aIN[m] = mfma16(a, w2, aIN[m]);
      }
    }
  }
  {  // h segment (K = HIDN, 32 k-tiles, 8 per wave)
    const int s0 = w * 8;
#pragma unroll
    for (int kk = 0; kk < 8; ++kk) {
      const int ks = s0 + kk;
      const u16* wb = swWh + (size_t)((ut * 32 + ks) * 3) * 512 + lane * 8;
      short8 w0 = ld8(wb), w1 = ld8(wb + 512), w2 = ld8(wb + 1024);
#pragma unroll
      for (int m = 0; m < NBT; ++m) {
        short8 a = ld8(hplain + (size_t)(mb0 + m * 16 + lo) * HIDN + ks * 32 + quad * 8);
        aR[m]  = mfma16(a, w0, aR[m]);
        aZ[m]  = mfma16(a, w1, aZ[m]);
        aHN[m] = mfma16(a, w2, aHN[m]);
      }
    }
  }
  // stage partials: lds[(w*NBT+m)*4*256 + type*256 + lane*4 + i]
#pragma unroll
  for (int m = 0; m < NBT; ++m) {
    float* b = lds + (size_t)((w * NBT + m) * 4) * 256 + lane * 4;
    *(f32x4*)(b)       = aR[m];
    *(f32x4*)(b + 256) = aZ[m];
    *(f32x4*)(b + 512) = aIN[m];
    *(f32x4*)(b + 768) = aHN[m];
  }
  __syncthreads();
  // reduce + gate math: thread -> (u = tid&15, bloc = tid>>4)
  const int u = tid & 15, bloc = tid >> 4;
  const int lidx = (bloc >> 2) * 64 + u * 4 + (bloc & 3);   // producer flat index
  const int ug = ut * 16 + u;
  const float b_r  = bi[ug] + bh[ug];
  const float b_z  = bi[HIDN + ug] + bh[HIDN + ug];
  const float b_in = bi[2 * HIDN + ug];
  const float b_hn = bh[2 * HIDN + ug];
#pragma unroll
  for (int m = 0; m < NBT; ++m) {
    float sR = 0.f, sZ = 0.f, sIN = 0.f, sHN = 0.f;
#pragma unroll
    for (int w4 = 0; w4 < 4; ++w4) {
      const float* q = lds + (size_t)((w4 * NBT + m) * 4) * 256 + lidx;
      sR += q[0]; sZ += q[256]; sIN += q[512]; sHN += q[768];
    }
    float r = sigm(sR + b_r);
    float z = sigm(sZ + b_z);
    float n = tanh_(sIN + b_in + r * (sHN + b_hn));
    const int b = mb0 + m * 16 + bloc;
    float h = (1.f - z) * n + z * hm[(size_t)b * HIDN + ug];
    hm[(size_t)b * HIDN + ug] = h;
    hout[(size_t)b * HIDN + ug] = f2bf(h);
    if (eo_bstride) st_out(outb, eo_base + (size_t)b * eo_bstride + ug, h, f32o);
  }
  __syncthreads();   // protect lds reuse next phase
}

// ---- FC phase: blocks = 16 out-tiles x 4 batch-tiles; waves split K ----
__device__ void fc_B(int ot, int mb0,
    const u16* __restrict__ hplain, const u16* __restrict__ swW,
    const float* __restrict__ bias,
    void* outb, size_t base, int out_bstride, u16* predb, int f32o, float* lds)
{
  const int tid = threadIdx.x;
  const int lane = tid & 63, w = tid >> 6;
  const int lo = lane & 15, quad = lane >> 4;
  f32x4 acc = {0.f,0.f,0.f,0.f};
  const int s0 = w * 8;
#pragma unroll
  for (int kk = 0; kk < 8; ++kk) {
    const int ks = s0 + kk;
    short8 wv = ld8(swW + (size_t)(ot * 32 + ks) * 512 + lane * 8);
    short8 a  = ld8(hplain + (size_t)(mb0 + lo) * HIDN + ks * 32 + quad * 8);
    acc = mfma16(a, wv, acc);
  }
  *(f32x4*)(lds + (size_t)w * 256 + lane * 4) = acc;
  __syncthreads();
  const int o = tid & 15, bloc = tid >> 4;
  const int lidx = (bloc >> 2) * 64 + o * 4 + (bloc & 3);
  const int og = ot * 16 + o;
  float s = bias[og];
#pragma unroll
  for (int w4 = 0; w4 < 4; ++w4) s += lds[(size_t)w4 * 256 + lidx];
  const int b = mb0 + bloc;
  st_out(outb, base + (size_t)b * out_bstride + og, s, f32o);
  predb[(size_t)b * IND + og] = f2bf(s);
  __syncthreads();
}

__global__ void __launch_bounds__(NTHR)
s2s_gru_main(P pr) {
  const int blk = blockIdx.x;
  __shared__ float lds[8192];      // 32 KB
  __shared__ int sflag[20];

  // ---- dtype detection ----
  {
    const int wv = threadIdx.x >> 6, ln = threadIdx.x & 63;
    for (int i = wv; i < 20; i += 4) {
      const unsigned* p = (const unsigned*)pr.in[i];
      unsigned wd = p[ln];
      unsigned e = (wd >> 7) & 0xFFu;
      unsigned long long m = __ballot(e >= 0x60u && e < 0xA0u);
      if (ln == 0) sflag[i] = (__popcll(m) >= 48) ? 1 : 0;
    }
  }
  __syncthreads();
  const int f32o = sflag[0] ? 0 : 1;

  // ---- staging: swizzle weights+src, biases fp32, zero state ----
  {
    const size_t gtid = (size_t)blk * NTHR + threadIdx.x;
    const size_t gs = (size_t)NBLK * NTHR;
    conv_src(gtid, gs, pr.in[0], g_bf + O_SRC, sflag[0]);
    conv_w(gtid, gs, pr.in[2],  g_bf + O_EWI0, IND,  3, HIDN, sflag[2]);
    conv_w(gtid, gs, pr.in[3],  g_bf + O_EWH0, HIDN, 3, HIDN, sflag[3]);
    conv_w(gtid, gs, pr.in[6],  g_bf + O_EWI1, HIDN, 3, HIDN, sflag[6]);
    conv_w(gtid, gs, pr.in[7],  g_bf + O_EWH1, HIDN, 3, HIDN, sflag[7]);
    conv_w(gtid, gs, pr.in[10], g_bf + O_DWI0, IND,  3, HIDN, sflag[10]);
    conv_w(gtid, gs, pr.in[11], g_bf + O_DWH0, HIDN, 3, HIDN, sflag[11]);
    conv_w(gtid, gs, pr.in[14], g_bf + O_DWI1, HIDN, 3, HIDN, sflag[14]);
    conv_w(gtid, gs, pr.in[15], g_bf + O_DWH1, HIDN, 3, HIDN, sflag[15]);
    conv_w(gtid, gs, pr.in[18], g_bf + O_FCW,  HIDN, 1, IND,  sflag[18]);
    conv_f(gtid, gs, pr.in[4],  g_fb + F_EBI0, 3*HIDN, sflag[4]);
    conv_f(gtid, gs, pr.in[5],  g_fb + F_EBH0, 3*HIDN, sflag[5]);
    conv_f(gtid, gs, pr.in[8],  g_fb + F_EBI1, 3*HIDN, sflag[8]);
    conv_f(gtid, gs, pr.in[9],  g_fb + F_EBH1, 3*HIDN, sflag[9]);
    conv_f(gtid, gs, pr.in[12], g_fb + F_DBI0, 3*HIDN, sflag[12]);
    conv_f(gtid, gs, pr.in[13], g_fb + F_DBH0, 3*HIDN, sflag[13]);
    conv_f(gtid, gs, pr.in[16], g_fb + F_DBI1, 3*HIDN, sflag[16]);
    conv_f(gtid, gs, pr.in[17], g_fb + F_DBH1, 3*HIDN, sflag[17]);
    conv_f(gtid, gs, pr.in[19], g_fb + F_FCB,  IND,    sflag[19]);
    for (size_t i = gtid; i < TOT_W; i += gs) g_state[i] = 0u;
  }
  grid_barrier();

  float* h0m = (float*)(g_state + H0M_W);
  float* h1m = (float*)(g_state + H1M_W);
  u16* y0r = (u16*)(g_state + Y0R_W);
  u16* h1b = (u16*)(g_state + H1B_W);
  u16* dh0 = (u16*)(g_state + DH0_W);
  u16* dh1 = (u16*)(g_state + DH1_W);
  u16* prd = (u16*)(g_state + PRD_W);

  const size_t EO_ENC = (size_t)BB * DT * IND;
  const size_t EO_DEC = EO_ENC + (size_t)BB * ET * HIDN;
  const size_t SH = (size_t)BB * HIDN;
  const size_t SP = (size_t)BB * IND;

  const int ut = blk & 63;

  // ---------------- encoder: pipelined, 257 phases ----------------
  for (int ph = 0; ph <= ET; ++ph) {
    if (blk < 128) {                       // layer 0: bt in {0,1}, 32 batches
      if (ph < ET) {
        const int bt = blk >> 6;
        gru_B<2, 8, true>(ut, bt * 32,
              g_bf + O_SRC + (size_t)ph * 16384,
              g_bf + O_EWI0, g_bf + O_EWH0,
              y0r + (size_t)(ph & 1) * SH,
              g_fb + F_EBI0, g_fb + F_EBH0, h0m,
              y0r + (size_t)((ph + 1) & 1) * SH,
              pr.out, 0, 0, f32o, lds);
      }
    } else {                               // layer 1
      if (ph >= 1) {
        const int t = ph - 1;
        const int bt = (blk >> 6) & 1;
        gru_B<2, 32, false>(ut, bt * 32,
              y0r + (size_t)(ph & 1) * SH,
              g_bf + O_EWI1, g_bf + O_EWH1,
              h1b + (size_t)(t & 1) * SH,
              g_fb + F_EBI1, g_fb + F_EBH1, h1m,
              h1b + (size_t)((t + 1) & 1) * SH,
              pr.out, EO_ENC + (size_t)t * HIDN, (size_t)ET * HIDN, f32o, lds);
      }
    }
    grid_barrier();
  }
  // dec l0 h-init = y0r slot 0; dec l1 h-init = h1b slot 0.

  // ---------------- decoder: 64 steps x 3 phases, full grid ----------------
  for (int s = 0; s < DT; ++s) {
    {  // layer 0: 64 ut x 4 bt
      const int bt = blk >> 6;
      const u16* x   = (s == 0) ? (prd + SP) : (prd + (size_t)((s - 1) & 1) * SP);
      const u16* hin = (s == 0) ? (y0r)      : (dh0 + (size_t)((s - 1) & 1) * SH);
      gru_B<1, 8, false>(ut, bt * 16, x,
            g_bf + O_DWI0, g_bf + O_DWH0, hin,
            g_fb + F_DBI0, g_fb + F_DBH0, h0m,
            dh0 + (size_t)(s & 1) * SH, pr.out, 0, 0, f32o, lds);
    }
    grid_barrier();
    {  // layer 1
      const int bt = blk >> 6;
      const u16* hin = (s == 0) ? (h1b) : (dh1 + (size_t)((s - 1) & 1) * SH);
      gru_B<1, 32, false>(ut, bt * 16,
            dh0 + (size_t)(s & 1) * SH,
            g_bf + O_DWI1, g_bf + O_DWH1, hin,
            g_fb + F_DBI1, g_fb + F_DBH1, h1m,
            dh1 + (size_t)(s & 1) * SH,
            pr.out, EO_DEC + (size_t)s * HIDN, (size_t)DT * HIDN, f32o, lds);
    }
    grid_barrier();
    if (blk < 64) {   // fc: 16 ot x 4 bt
      fc_B(blk & 15, (blk >> 4) * 16,
           dh1 + (size_t)(s & 1) * SH, g_bf + O_FCW, g_fb + F_FCB,
           pr.out, (size_t)s * IND, DT * IND,
           prd + (size_t)(s & 1) * SP, f32o, lds);
    }
    grid_barrier();
  }
}

extern "C" void kernel_launch(void* const* d_in, const int* in_sizes, int n_in,
                              void* d_out, int out_size, void* d_ws, size_t ws_size,
                              hipStream_t stream) {
  P p;
  for (int i = 0; i < 20; ++i) p.in[i] = d_in[i];
  p.out = d_out;
  s2s_gru_main<<<dim3(NBLK), dim3(NTHR), 0, stream>>>(p);
}